// Round 1
// baseline (732.555 us; speedup 1.0000x reference)
//
#include <hip/hip_runtime.h>

// Performer FAVOR+ linear attention, MFMA bf16 hi/lo-split implementation.
// b*h=128 heads, n=4096, d=64, m=256, fp32 in/out.

#define BH 128
#define NN 4096
#define DD 64
#define MM 256
#define NORM 0.35355339059327373f   // 64^-0.25
#define EPS 1e-4f

typedef unsigned short u16;
typedef __attribute__((ext_vector_type(8))) short bfrag;   // 8 x bf16
typedef __attribute__((ext_vector_type(4))) float ffrag;   // 4 x f32
#define MFMA16(A,B,C) __builtin_amdgcn_mfma_f32_16x16x32_bf16(A,B,C,0,0,0)

__device__ __forceinline__ float u2f(u16 h){ return __uint_as_float(((unsigned)h)<<16); }
__device__ __forceinline__ void splitf(float x, u16 &h, u16 &l){
    unsigned uh = __float_as_uint(x) & 0xffff0000u;
    h = (u16)(uh >> 16);
    float r = x - __uint_as_float(uh);
    l = (u16)(__float_as_uint(r) >> 16);
}

// ---------------- P0a: split projection ----------------
__global__ void p0_proj(const float* __restrict__ proj, u16* __restrict__ phi, u16* __restrict__ plo){
    int idx = blockIdx.x*256 + threadIdx.x;   // 16384 total
    u16 h,l; splitf(proj[idx], h, l);
    phi[idx] = h; plo[idx] = l;
}

// ---------------- P0b: V -> VT (hi/lo) + vsum ----------------
__global__ __launch_bounds__(256) void p0_vt(const float* __restrict__ vin,
        u16* __restrict__ vthi, u16* __restrict__ vtlo, float* __restrict__ vsum){
    int head = blockIdx.x >> 6;
    int n0 = (blockIdx.x & 63) * 64;
    int t = threadIdx.x;
    __shared__ float tile[64][65];
    {
        int row = t >> 2, c0 = (t & 3) * 16;
        const float* src = vin + ((size_t)head*NN + n0 + row)*64 + c0;
        #pragma unroll
        for (int i=0;i<4;++i){
            float4 x = *(const float4*)(src + i*4);
            tile[row][c0+i*4+0]=x.x; tile[row][c0+i*4+1]=x.y;
            tile[row][c0+i*4+2]=x.z; tile[row][c0+i*4+3]=x.w;
        }
    }
    __syncthreads();
    {
        int e = t >> 2, nq = (t & 3) * 16;
        float s = 0.f;
        unsigned ph[8], pl[8];
        #pragma unroll
        for (int jj=0;jj<8;++jj){
            float x0 = tile[nq+jj*2+0][e];
            float x1 = tile[nq+jj*2+1][e];
            s += x0 + x1;
            u16 h0,l0,h1,l1; splitf(x0,h0,l0); splitf(x1,h1,l1);
            ph[jj] = (unsigned)h0 | ((unsigned)h1<<16);
            pl[jj] = (unsigned)l0 | ((unsigned)l1<<16);
        }
        size_t base = ((size_t)head*64 + e)*NN + n0 + nq;
        uint4 a0; a0.x=ph[0]; a0.y=ph[1]; a0.z=ph[2]; a0.w=ph[3];
        uint4 a1; a1.x=ph[4]; a1.y=ph[5]; a1.z=ph[6]; a1.w=ph[7];
        uint4 b0; b0.x=pl[0]; b0.y=pl[1]; b0.z=pl[2]; b0.w=pl[3];
        uint4 b1; b1.x=pl[4]; b1.y=pl[5]; b1.z=pl[6]; b1.w=pl[7];
        *(uint4*)(vthi + base)     = a0;
        *(uint4*)(vthi + base + 8) = a1;
        *(uint4*)(vtlo + base)     = b0;
        *(uint4*)(vtlo + base + 8) = b1;
        s += __shfl_xor(s, 1);
        s += __shfl_xor(s, 2);
        if ((t & 3) == 0) atomicAdd(vsum + head*64 + e, s);
    }
}

// ---------------- KC: K-side dash GEMM -> exp (flash max) -> ctx^T GEMM ----------------
// grid 1024 = 128 heads x 8 chunks (512 n each). 256 thr = 4 waves.
__global__ __launch_bounds__(256) __attribute__((amdgpu_waves_per_eu(2,2)))
void kc_kernel(
        const float* __restrict__ kin, const u16* __restrict__ phi, const u16* __restrict__ plo,
        const u16* __restrict__ vthi, const u16* __restrict__ vtlo,
        float* __restrict__ ctxPart, float* __restrict__ mbArr)
{
    const int blk  = blockIdx.x;
    const int head = blk >> 3;
    const int n0   = (blk & 7) * 512;
    const int t    = threadIdx.x;
    const int w    = t >> 6;
    const int lane = t & 63;
    const int qd   = lane >> 4;
    const int li   = lane & 15;

    __shared__ __attribute__((aligned(16))) u16 knh[32*64], knl[32*64];
    __shared__ __attribute__((aligned(16))) u16 bsh[256*32], bsl[256*32];
    __shared__ float diag_s[32];
    __shared__ float wmax[4];

    // projection B-frags for this wave's m-quarter (held in regs)
    bfrag pf[4][2][2];
    #pragma unroll
    for (int mt=0;mt<4;++mt){
        int m = w*64 + mt*16 + li;
        #pragma unroll
        for (int ks=0;ks<2;++ks){
            pf[mt][ks][0] = *(const bfrag*)(phi + m*64 + ks*32 + qd*8);
            pf[mt][ks][1] = *(const bfrag*)(plo + m*64 + ks*32 + qd*8);
        }
    }

    ffrag acc[4][4];
    #pragma unroll
    for (int et=0;et<4;++et)
        #pragma unroll
        for (int mt=0;mt<4;++mt){ ffrag z = {0.f,0.f,0.f,0.f}; acc[et][mt] = z; }
    float ks[4] = {0.f,0.f,0.f,0.f};
    float M = -3.0e38f;

    const float* kg = kin + ((size_t)head*NN + n0)*64;

    for (int sub=0; sub<16; ++sub){
        // ---- stage Kn subtile [32 n][64 d], swizzled, + diag via shfl
        {
            int row = t >> 3;
            int g   = t & 7;
            const float* src = kg + (size_t)(sub*32 + row)*64 + g*8;
            float4 x0 = *(const float4*)(src);
            float4 x1 = *(const float4*)(src + 4);
            float xs[8] = {x0.x,x0.y,x0.z,x0.w,x1.x,x1.y,x1.z,x1.w};
            bfrag hv, lv;
            float ss = 0.f;
            #pragma unroll
            for (int j=0;j<8;++j){
                float xn = xs[j]*NORM;
                ss += xn*xn;
                u16 hh,ll; splitf(xn,hh,ll);
                hv[j] = (short)hh; lv[j] = (short)ll;
            }
            int gs = g ^ (row & 7);
            *(bfrag*)(knh + row*64 + gs*8) = hv;
            *(bfrag*)(knl + row*64 + gs*8) = lv;
            ss += __shfl_xor(ss, 1);
            ss += __shfl_xor(ss, 2);
            ss += __shfl_xor(ss, 4);
            if ((t & 7) == 0) diag_s[row] = 0.5f*ss;
        }
        __syncthreads();

        // ---- GEMM1: dash[32 n][256 m] (this wave: its m-quarter)
        ffrag d1[2][4];
        #pragma unroll
        for (int nt=0;nt<2;++nt)
            #pragma unroll
            for (int mt=0;mt<4;++mt){ ffrag z = {0.f,0.f,0.f,0.f}; d1[nt][mt] = z; }
        #pragma unroll
        for (int nt=0;nt<2;++nt){
            int n = nt*16 + li;
            bfrag ah[2], al[2];
            #pragma unroll
            for (int kss=0;kss<2;++kss){
                int gp = (kss*4 + qd) ^ (n & 7);
                ah[kss] = *(const bfrag*)(knh + n*64 + gp*8);
                al[kss] = *(const bfrag*)(knl + n*64 + gp*8);
            }
            #pragma unroll
            for (int mt=0;mt<4;++mt){
                #pragma unroll
                for (int kss=0;kss<2;++kss){
                    d1[nt][mt] = MFMA16(ah[kss], pf[mt][kss][0], d1[nt][mt]);
                    d1[nt][mt] = MFMA16(ah[kss], pf[mt][kss][1], d1[nt][mt]);
                    d1[nt][mt] = MFMA16(al[kss], pf[mt][kss][0], d1[nt][mt]);
                }
            }
        }

        // ---- subtile max (block-wide)
        float mx = -3.0e38f;
        #pragma unroll
        for (int nt=0;nt<2;++nt)
            #pragma unroll
            for (int mt=0;mt<4;++mt)
                #pragma unroll
                for (int rg=0;rg<4;++rg) mx = fmaxf(mx, d1[nt][mt][rg]);
        mx = fmaxf(mx, __shfl_xor(mx, 1));
        mx = fmaxf(mx, __shfl_xor(mx, 2));
        mx = fmaxf(mx, __shfl_xor(mx, 4));
        mx = fmaxf(mx, __shfl_xor(mx, 8));
        mx = fmaxf(mx, __shfl_xor(mx, 16));
        mx = fmaxf(mx, __shfl_xor(mx, 32));
        if (lane == 0) wmax[w] = mx;
        __syncthreads();
        float Ms = fmaxf(fmaxf(wmax[0],wmax[1]), fmaxf(wmax[2],wmax[3]));
        float Mn = fmaxf(M, Ms);
        float r  = __expf(M - Mn);
        M = Mn;
        #pragma unroll
        for (int mt=0;mt<4;++mt) ks[mt] *= r;
        #pragma unroll
        for (int et=0;et<4;++et)
            #pragma unroll
            for (int mt=0;mt<4;++mt)
                #pragma unroll
                for (int rg=0;rg<4;++rg) acc[et][mt][rg] *= r;

        // ---- features -> Bs[m 256][n 32] (transposed, swizzled), + ksum partials
        float sl[4] = {0.f,0.f,0.f,0.f};
        #pragma unroll
        for (int nt=0;nt<2;++nt){
            float d4[4];
            #pragma unroll
            for (int rg=0;rg<4;++rg) d4[rg] = diag_s[nt*16 + qd*4 + rg];
            #pragma unroll
            for (int mt=0;mt<4;++mt){
                int m = w*64 + mt*16 + li;
                u16 h4[4], l4[4];
                #pragma unroll
                for (int rg=0;rg<4;++rg){
                    float f = __expf(d1[nt][mt][rg] - d4[rg] - M);
                    sl[mt] += f;
                    splitf(f, h4[rg], l4[rg]);
                }
                int g  = nt*2 + (qd>>1);
                int gp = g ^ ((m>>1)&3);
                int off = m*32 + gp*8 + (qd&1)*4;
                *(ushort4*)(bsh + off) = make_ushort4(h4[0],h4[1],h4[2],h4[3]);
                *(ushort4*)(bsl + off) = make_ushort4(l4[0],l4[1],l4[2],l4[3]);
            }
        }
        #pragma unroll
        for (int mt=0;mt<4;++mt){
            float v = sl[mt];
            v += __shfl_xor(v, 16);
            v += __shfl_xor(v, 32);
            ks[mt] += v;
        }
        __syncthreads();

        // ---- ctx^T GEMM: acc[e][m] += VT[e][n-chunk] * feat[m][n-chunk]
        bfrag bh[4], bl[4];
        #pragma unroll
        for (int mt=0;mt<4;++mt){
            int m = w*64 + mt*16 + li;
            int gp = qd ^ ((m>>1)&3);
            bh[mt] = *(const bfrag*)(bsh + m*32 + gp*8);
            bl[mt] = *(const bfrag*)(bsl + m*32 + gp*8);
        }
        #pragma unroll
        for (int et=0;et<4;++et){
            int e = et*16 + li;
            size_t vb = ((size_t)head*64 + e)*NN + n0 + sub*32 + qd*8;
            bfrag avh = *(const bfrag*)(vthi + vb);
            bfrag avl = *(const bfrag*)(vtlo + vb);
            #pragma unroll
            for (int mt=0;mt<4;++mt){
                acc[et][mt] = MFMA16(avh, bh[mt], acc[et][mt]);
                acc[et][mt] = MFMA16(avh, bl[mt], acc[et][mt]);
                acc[et][mt] = MFMA16(avl, bh[mt], acc[et][mt]);
            }
        }
        __syncthreads();
    }

    // ---- epilogue: partials [blk][65][256] (row 64 = ksum)
    float* P = ctxPart + (size_t)blk * (65*256);
    #pragma unroll
    for (int et=0;et<4;++et)
        #pragma unroll
        for (int mt=0;mt<4;++mt)
            #pragma unroll
            for (int rg=0;rg<4;++rg){
                int e = et*16 + qd*4 + rg;
                int m = w*64 + mt*16 + li;
                P[e*256 + m] = acc[et][mt][rg];
            }
    if (qd == 0){
        #pragma unroll
        for (int mt=0;mt<4;++mt) P[64*256 + w*64 + mt*16 + li] = ks[mt];
    }
    if (t == 0) mbArr[blk] = M;
}

// ---------------- kred ----------------
__global__ __launch_bounds__(256) void kred(const float* __restrict__ ctxPart,
        const float* __restrict__ mbArr, const float* __restrict__ vsum,
        u16* __restrict__ ctxh, u16* __restrict__ ctxl, float* __restrict__ ksumG){
    int head = blockIdx.x / 65;
    int e = blockIdx.x % 65;
    int m = threadIdx.x;
    float mb[8];
    float mk = -3.0e38f;
    #pragma unroll
    for (int c=0;c<8;++c){ mb[c] = mbArr[head*8+c]; mk = fmaxf(mk, mb[c]); }
    float s = 0.f;
    #pragma unroll
    for (int c=0;c<8;++c){
        float sc = __expf(mb[c] - mk);
        s += sc * ctxPart[((size_t)(head*8+c)*65 + e)*256 + m];
    }
    if (e == 64){
        ksumG[head*256 + m] = s + 4096.0f*EPS;
    } else {
        float val = s + EPS * vsum[head*64 + e];
        u16 h,l; splitf(val,h,l);
        ctxh[((size_t)head*64 + e)*256 + m] = h;
        ctxl[((size_t)head*64 + e)*256 + m] = l;
    }
}

// ---------------- K3: Q-side dash GEMM -> exp -> output GEMM (n-chunked f) ----
// grid 8192; head-XCD swizzle. 64 q-rows per block, 4 waves.
// GEMM1: A=proj (rows=m), B=qn (cols=n) -> d1[mt][nt]: m-contiguous per thread.
// Features staged in TWO n-chunks of 32 rows (f[32][256] hi/lo = 32KB LDS) so
// the block fits 4x per CU (was 2x at 64KB). GEMM2 runs its full m-loop per
// chunk; ctx fragments re-read per chunk (L2-hot, 256B/thread). All 4 waves
// stay busy in the feature phase (chunking is over n, not m).
__global__ __launch_bounds__(256) __attribute__((amdgpu_waves_per_eu(4,4)))
void k3_kernel(
        const float* __restrict__ qin, const u16* __restrict__ phi, const u16* __restrict__ plo,
        const u16* __restrict__ ctxh, const u16* __restrict__ ctxl,
        const float* __restrict__ ksumG, float* __restrict__ out)
{
    const int bx   = blockIdx.x;
    const int head = (bx & 7) + 8 * ((bx >> 3) & 15);   // heads % 8 colocated per XCD
    const int n0   = (bx >> 7) * 64;
    const int t    = threadIdx.x;
    const int w    = t >> 6;
    const int lane = t & 63;
    const int qd   = lane >> 4;
    const int li   = lane & 15;

    __shared__ __attribute__((aligned(16))) u16 SM[16384];  // 32KB
    u16* qnh = SM;            // [64][64]  (phase 1, aliased)
    u16* qnl = SM + 4096;
    u16* fh  = SM;            // [32][256] (phase 2+, per n-chunk)
    u16* fl  = SM + 8192;
    __shared__ float diagq[64], drm[64], dinvs[64], wm[4][64];

    // ---- stage Qn [64][64] hi/lo (swizzled) + diagq
    {
        int row = t >> 2;
        const float* src = qin + ((size_t)head*NN + n0 + row)*64 + (t&3)*16;
        float ss = 0.f;
        #pragma unroll
        for (int gi=0; gi<2; ++gi){
            int g = (t&3)*2 + gi;
            float4 x0 = *(const float4*)(src + gi*8);
            float4 x1 = *(const float4*)(src + gi*8 + 4);
            float xs[8] = {x0.x,x0.y,x0.z,x0.w,x1.x,x1.y,x1.z,x1.w};
            bfrag hv, lv;
            #pragma unroll
            for (int j=0;j<8;++j){
                float xn = xs[j]*NORM;
                ss += xn*xn;
                u16 hh,ll; splitf(xn,hh,ll);
                hv[j] = (short)hh; lv[j] = (short)ll;
            }
            int gs = g ^ (row & 7);
            *(bfrag*)(qnh + row*64 + gs*8) = hv;
            *(bfrag*)(qnl + row*64 + gs*8) = lv;
        }
        ss += __shfl_xor(ss, 1);
        ss += __shfl_xor(ss, 2);
        if ((t&3) == 0) diagq[row] = 0.5f*ss;
    }

    // per-thread ksum values for its 16 m's (m = w*64+mt*16+qd*4+rg)
    float4 ks4[4];
    #pragma unroll
    for (int mt=0;mt<4;++mt)
        ks4[mt] = *(const float4*)(ksumG + head*256 + w*64 + mt*16 + qd*4);
    __syncthreads();

    // ---- GEMM1 (kss-outer; every fragment loaded exactly once)
    ffrag d1[4][4];   // [mt][nt]: m = w*64+mt*16+qd*4+rg, n = nt*16+li
    #pragma unroll
    for (int mt=0;mt<4;++mt)
        #pragma unroll
        for (int nt=0;nt<4;++nt){ ffrag z = {0.f,0.f,0.f,0.f}; d1[mt][nt] = z; }
    #pragma unroll
    for (int kss=0;kss<2;++kss){
        bfrag pfh[4], pfl[4];
        #pragma unroll
        for (int mt=0;mt<4;++mt){
            int m = w*64 + mt*16 + li;
            pfh[mt] = *(const bfrag*)(phi + m*64 + kss*32 + qd*8);
            pfl[mt] = *(const bfrag*)(plo + m*64 + kss*32 + qd*8);
        }
        #pragma unroll
        for (int nt=0;nt<4;++nt){
            int n = nt*16 + li;
            int gp = (kss*4 + qd) ^ (n & 7);
            bfrag bh = *(const bfrag*)(qnh + n*64 + gp*8);
            bfrag bl = *(const bfrag*)(qnl + n*64 + gp*8);
            #pragma unroll
            for (int mt=0;mt<4;++mt){
                d1[mt][nt] = MFMA16(pfh[mt], bh, d1[mt][nt]);
                d1[mt][nt] = MFMA16(pfh[mt], bl, d1[mt][nt]);
                d1[mt][nt] = MFMA16(pfl[mt], bh, d1[mt][nt]);
            }
        }
    }

    // ---- per-n max over m: in-thread (16 vals) + qd-shfl + cross-wave LDS
    #pragma unroll
    for (int nt=0;nt<4;++nt){
        float mx = -3.0e38f;
        #pragma unroll
        for (int mt=0;mt<4;++mt)
            #pragma unroll
            for (int rg=0;rg<4;++rg) mx = fmaxf(mx, d1[mt][nt][rg]);
        mx = fmaxf(mx, __shfl_xor(mx, 16));
        mx = fmaxf(mx, __shfl_xor(mx, 32));
        if (qd == 0) wm[w][nt*16 + li] = mx;
    }
    __syncthreads();
    if (t < 64)
        drm[t] = diagq[t] + fmaxf(fmaxf(wm[0][t], wm[1][t]), fmaxf(wm[2][t], wm[3][t]));
    __syncthreads();

    // ---- GEMM2 accumulators + ctx base pointers
    ffrag a2[4];   // [nt]: n = nt*16+qd*4+rg, e = w*16+li
    #pragma unroll
    for (int nt=0;nt<4;++nt){ ffrag z = {0.f,0.f,0.f,0.f}; a2[nt] = z; }
    const u16* cbh = ctxh + (size_t)head*64*256 + (w*16 + li)*256;
    const u16* cbl = ctxl + (size_t)head*64*256 + (w*16 + li)*256;

    // ---- two n-chunks: {features+denoms for 32 n -> f[32][256]} then GEMM2
    #pragma unroll
    for (int ch=0; ch<2; ++ch){
        #pragma unroll
        for (int ntl=0; ntl<2; ++ntl){
            const int nt = ch*2 + ntl;
            int n = nt*16 + li;
            float dr = drm[n];
            float ds = 0.f;
            #pragma unroll
            for (int mt=0;mt<4;++mt){
                float fv[4];
                u16 h4[4], l4[4];
                #pragma unroll
                for (int rg=0;rg<4;++rg){
                    fv[rg] = __expf(d1[mt][nt][rg] - dr) + EPS;
                    splitf(fv[rg], h4[rg], l4[rg]);
                }
                ds += fv[0]*ks4[mt].x + fv[1]*ks4[mt].y + fv[2]*ks4[mt].z + fv[3]*ks4[mt].w;
                int G  = w*8 + mt*2 + (qd>>1);       // (m0)>>3, m0 = w*64+mt*16+qd*4
                int Gp = G ^ (li & 7);
                int off = (ntl*16 + li)*256 + Gp*8 + (qd&1)*4;   // u16 units
                *(ushort4*)(fh + off) = make_ushort4(h4[0],h4[1],h4[2],h4[3]);
                *(ushort4*)(fl + off) = make_ushort4(l4[0],l4[1],l4[2],l4[3]);
            }
            ds += __shfl_xor(ds, 16);
            ds += __shfl_xor(ds, 32);
            if (qd == 0) wm[w][n] = ds;
        }
        __syncthreads();

        // denom for this chunk's 32 n (read in epilogue, after final barrier)
        if (t < 32){
            int n = ch*32 + t;
            dinvs[n] = 1.0f / (wm[0][n] + wm[1][n] + wm[2][n] + wm[3][n]);
        }

        // GEMM2 over full m for this chunk's 32 n; wave = e-quarter
        #pragma unroll
        for (int ksm=0; ksm<8; ++ksm){
            bfrag chv = *(const bfrag*)(cbh + ksm*32 + qd*8);
            bfrag clv = *(const bfrag*)(cbl + ksm*32 + qd*8);
            #pragma unroll
            for (int ntl=0; ntl<2; ++ntl){
                int nl = ntl*16 + li;
                int Gp = (ksm*4 + qd) ^ (li & 7);
                bfrag ah2 = *(const bfrag*)(fh + nl*256 + Gp*8);
                bfrag al2 = *(const bfrag*)(fl + nl*256 + Gp*8);
                a2[ch*2+ntl] = MFMA16(ah2, chv, a2[ch*2+ntl]);
                a2[ch*2+ntl] = MFMA16(ah2, clv, a2[ch*2+ntl]);
                a2[ch*2+ntl] = MFMA16(al2, chv, a2[ch*2+ntl]);
            }
        }
        __syncthreads();   // ch=0: before f overwrite; ch=1: before epilogue (dinvs)
    }

    // ---- epilogue
    float* og = out + ((size_t)head*NN + n0)*64;
    #pragma unroll
    for (int nt=0;nt<4;++nt){
        #pragma unroll
        for (int rg=0;rg<4;++rg){
            int n = nt*16 + qd*4 + rg;
            og[(size_t)n*64 + w*16 + li] = a2[nt][rg] * dinvs[n];
        }
    }
}

extern "C" void kernel_launch(void* const* d_in, const int* in_sizes, int n_in,
                              void* d_out, int out_size, void* d_ws, size_t ws_size,
                              hipStream_t stream) {
    const float* q    = (const float*)d_in[0];
    const float* k    = (const float*)d_in[1];
    const float* v    = (const float*)d_in[2];
    const float* proj = (const float*)d_in[3];
    float* out = (float*)d_out;

    char* wp = (char*)d_ws;
    u16* phi     = (u16*)wp;  wp += (size_t)MM*DD*2;
    u16* plo     = (u16*)wp;  wp += (size_t)MM*DD*2;
    u16* vthi    = (u16*)wp;  wp += (size_t)BH*64*NN*2;
    u16* vtlo    = (u16*)wp;  wp += (size_t)BH*64*NN*2;
    float* vsum  = (float*)wp; wp += (size_t)BH*64*4;
    float* mbArr = (float*)wp; wp += (size_t)1024*4;
    float* ctxPart = (float*)wp; wp += (size_t)1024*65*256*4;
    u16* ctxh    = (u16*)wp;  wp += (size_t)BH*64*256*2;
    u16* ctxl    = (u16*)wp;  wp += (size_t)BH*64*256*2;
    float* ksumG = (float*)wp; wp += (size_t)BH*256*4;

    hipMemsetAsync(vsum, 0, (size_t)BH*64*4, stream);
    p0_proj<<<64, 256, 0, stream>>>(proj, phi, plo);
    p0_vt<<<BH*64, 256, 0, stream>>>(v, vthi, vtlo, vsum);
    kc_kernel<<<1024, 256, 0, stream>>>(k, phi, plo, vthi, vtlo, ctxPart, mbArr);
    kred<<<BH*65, 256, 0, stream>>>(ctxPart, mbArr, vsum, ctxh, ctxl, ksumG);
    k3_kernel<<<BH*64, 256, 0, stream>>>(q, phi, plo, ctxh, ctxl, ksumG, out);
}